// Round 4
// baseline (199.303 us; speedup 1.0000x reference)
//
#include <hip/hip_runtime.h>
#include <hip/hip_bf16.h>

typedef unsigned short ushort_t;
typedef __attribute__((ext_vector_type(8))) short short8;
typedef __attribute__((ext_vector_type(4))) float f32x4;

constexpr int B  = 2;
constexpr int T  = 2048;
constexpr int E  = 768;
constexpr int H  = 12;
constexpr int HD = 64;

__device__ __forceinline__ ushort_t f2bf(float x) {
  unsigned int u = __float_as_uint(x);
  u += 0x7fffu + ((u >> 16) & 1u);
  return (ushort_t)(u >> 16);
}

__device__ __forceinline__ unsigned int pack_bf2(float a, float b) {
  __hip_bfloat162 h = __float22bfloat162_rn(float2{a, b});
  return *(unsigned int*)&h;
}

// XOR-swizzled LDS index, 64-ushort rows (attention): 16B chunks, chunk ^= row&7.
__device__ __forceinline__ int swz(int row, int col) {
  return row * 64 + ((((col >> 3) ^ (row & 7)) << 3) | (col & 7));
}
// XOR-swizzled LDS index, 32-ushort rows (GEMM k-step 32): chunk ^= row&3.
__device__ __forceinline__ int swz32(int row, int col) {
  return row * 32 + ((((col >> 3) ^ (row & 3)) << 3) | (col & 7));
}

// ---------------------------------------------------------------------------
// Fused fp32 -> bf16 convert for X + 4 weight matrices (one launch).
// ---------------------------------------------------------------------------
__global__ __launch_bounds__(256) void cvt_all(
    const float* __restrict__ X,  const float* __restrict__ Wq,
    const float* __restrict__ Wk, const float* __restrict__ Wv,
    const float* __restrict__ Wo,
    ushort_t* __restrict__ Xb,  ushort_t* __restrict__ Wqb,
    ushort_t* __restrict__ Wkb, ushort_t* __restrict__ Wvb,
    ushort_t* __restrict__ Wob)
{
  constexpr int NX4 = (B * T * E) / 4;
  constexpr int NW4 = (E * E) / 4;
  int i = blockIdx.x * 256 + threadIdx.x;
  const float* s; ushort_t* d; int j;
  if (i < NX4) { s = X; d = Xb; j = i; }
  else {
    int t = i - NX4;
    int w = t / NW4; j = t - w * NW4;
    s = (w == 0) ? Wq : (w == 1) ? Wk : (w == 2) ? Wv : Wo;
    d = (w == 0) ? Wqb : (w == 1) ? Wkb : (w == 2) ? Wvb : Wob;
  }
  float4 v = ((const float4*)s)[j];
  ushort4 o;
  o.x = f2bf(v.x); o.y = f2bf(v.y); o.z = f2bf(v.z); o.w = f2bf(v.w);
  ((ushort4*)d)[j] = o;
}

// ---------------------------------------------------------------------------
// QKV projection, bf16 MFMA. Tile 128(M)x128(N), K-step 32, 2x2 waves
// (64x64 each). Rotary fused. q/k -> (bh,t,d); v -> transposed (bh,d,t).
// ---------------------------------------------------------------------------
__global__ __launch_bounds__(256) void qkv_gemm(
    const ushort_t* __restrict__ Xb,
    const ushort_t* __restrict__ Wqb, const ushort_t* __restrict__ Wkb,
    const ushort_t* __restrict__ Wvb, const float* __restrict__ rope,
    ushort_t* __restrict__ qb, ushort_t* __restrict__ kb, ushort_t* __restrict__ vtb)
{
  // union: staging (Xs 128x32 | Ws 128x32 = 16 KB)  /  Tr (2 heads x 64 x 136 = 34.8 KB)
  __shared__ __align__(16) ushort_t smem[2 * 64 * 136];
  ushort_t* Xs = smem;
  ushort_t* Ws = smem + 128 * 32;
  const int tid  = threadIdx.x;
  const int wave = tid >> 6;
  const int lane = tid & 63;
  const int l15  = lane & 15, quad = lane >> 4;
  const int ww = wave >> 1, wn = wave & 1;
  const int n0 = blockIdx.x * 128;
  const int m0 = blockIdx.y * 128;
  const int z  = blockIdx.z;
  const ushort_t* Wt = (z == 0) ? Wqb : (z == 1) ? Wkb : Wvb;

  f32x4 acc[4][4];
  #pragma unroll
  for (int i = 0; i < 4; ++i)
    #pragma unroll
    for (int j = 0; j < 4; ++j) acc[i][j] = (f32x4){0.f, 0.f, 0.f, 0.f};

  const int srow = tid >> 1, scc = (tid & 1) * 16;

  for (int k0 = 0; k0 < E; k0 += 32) {
    uint4 xa = *(const uint4*)(Xb + (size_t)(m0 + srow) * E + k0 + scc);
    uint4 xc = *(const uint4*)(Xb + (size_t)(m0 + srow) * E + k0 + scc + 8);
    uint4 wa = *(const uint4*)(Wt + (size_t)(n0 + srow) * E + k0 + scc);
    uint4 wc = *(const uint4*)(Wt + (size_t)(n0 + srow) * E + k0 + scc + 8);
    *(uint4*)&Xs[swz32(srow, scc)]     = xa;
    *(uint4*)&Xs[swz32(srow, scc + 8)] = xc;
    *(uint4*)&Ws[swz32(srow, scc)]     = wa;
    *(uint4*)&Ws[swz32(srow, scc + 8)] = wc;
    __syncthreads();
    short8 a[4];
    #pragma unroll
    for (int mt = 0; mt < 4; ++mt)
      a[mt] = *(const short8*)&Xs[swz32(ww * 64 + mt * 16 + l15, quad * 8)];
    #pragma unroll
    for (int nt = 0; nt < 4; ++nt) {
      short8 bb = *(const short8*)&Ws[swz32(wn * 64 + nt * 16 + l15, quad * 8)];
      #pragma unroll
      for (int mt = 0; mt < 4; ++mt)
        acc[mt][nt] = __builtin_amdgcn_mfma_f32_16x16x32_bf16(a[mt], bb, acc[mt][nt], 0, 0, 0);
    }
    __syncthreads();
  }

  const int h = blockIdx.x * 2 + wn;
  const float qscale = (z == 0) ? 0.125f : 1.0f;
  if (z < 2) {
    ushort_t* dst = (z == 0) ? qb : kb;
    #pragma unroll
    for (int mt = 0; mt < 4; ++mt) {
      #pragma unroll
      for (int r = 0; r < 4; ++r) {
        int m = m0 + ww * 64 + mt * 16 + quad * 4 + r;
        int b = m >> 11, t = m & (T - 1);
        float s0 = acc[mt][0][r] * qscale;
        float s1 = acc[mt][1][r] * qscale;
        float s2 = acc[mt][2][r] * qscale;
        float s3 = acc[mt][3][r] * qscale;
        float f0 = rope[t * 32 + l15], f1 = rope[t * 32 + 16 + l15];
        float c0v, sn0, c1v, sn1;
        __sincosf(f0, &sn0, &c0v);
        __sincosf(f1, &sn1, &c1v);
        size_t base = ((size_t)(b * H + h) * T + t) * HD;
        dst[base + l15]      = f2bf(s0 * c0v - s1 * sn0);
        dst[base + 16 + l15] = f2bf(s1 * c1v + s0 * sn1);
        dst[base + 32 + l15] = f2bf(s2);
        dst[base + 48 + l15] = f2bf(s3);
      }
    }
  } else {
    // V: rotary in regs, transpose via LDS (per-head region), store (bh,d,t)
    ushort_t* Tr = smem + wn * (64 * 136);
    #pragma unroll
    for (int mt = 0; mt < 4; ++mt) {
      #pragma unroll
      for (int r = 0; r < 4; ++r) {
        int mloc = ww * 64 + mt * 16 + quad * 4 + r;
        int t = (m0 + mloc) & (T - 1);
        float s0 = acc[mt][0][r], s1 = acc[mt][1][r];
        float f0 = rope[t * 32 + l15], f1 = rope[t * 32 + 16 + l15];
        float c0v, sn0, c1v, sn1;
        __sincosf(f0, &sn0, &c0v);
        __sincosf(f1, &sn1, &c1v);
        Tr[(l15)      * 136 + mloc] = f2bf(s0 * c0v - s1 * sn0);
        Tr[(16 + l15) * 136 + mloc] = f2bf(s1 * c1v + s0 * sn1);
        Tr[(32 + l15) * 136 + mloc] = f2bf(acc[mt][2][r]);
        Tr[(48 + l15) * 136 + mloc] = f2bf(acc[mt][3][r]);
      }
    }
    __syncthreads();
    int b = m0 >> 11, t0 = m0 & (T - 1);
    int hh = tid >> 7, drow = (tid >> 1) & 63, c0 = (tid & 1) * 64;
    const ushort_t* Trh = smem + hh * (64 * 136);
    size_t obase = ((size_t)(b * H + blockIdx.x * 2 + hh) * HD + drow) * (size_t)T + t0 + c0;
    #pragma unroll
    for (int c = 0; c < 64; c += 8)
      *(uint4*)(vtb + obase + c) = *(const uint4*)&Trh[drow * 136 + c0 + c];
  }
}

// ---------------------------------------------------------------------------
// Flash attention. Block = 128 q-rows x bh; 4 waves, wave owns 32 q.
// Double-buffered K/V (ONE barrier per tile), XOR-swizzled LDS (conflict-free
// b128), Q fragments from global, static max, per-lane denominator.
// ---------------------------------------------------------------------------
__global__ __launch_bounds__(256, 3) void attn_kernel(
    const ushort_t* __restrict__ qbuf, const ushort_t* __restrict__ kbuf,
    const ushort_t* __restrict__ vtbuf, ushort_t* __restrict__ cbuf)
{
  __shared__ __align__(16) ushort_t Ks[2][64 * 64];
  __shared__ __align__(16) ushort_t Vt[2][64 * 64];
  __shared__ __align__(16) ushort_t Ps[128 * 64];
  const int tid  = threadIdx.x;
  const int wave = tid >> 6;
  const int lane = tid & 63;
  const int l15  = lane & 15, quad = lane >> 4;
  const int q0 = blockIdx.x * 128;
  const int bh = blockIdx.y;
  const ushort_t* Qg = qbuf  + (size_t)bh * T * HD;
  const ushort_t* Kg = kbuf  + (size_t)bh * T * HD;
  const ushort_t* Vg = vtbuf + (size_t)bh * HD * T;

  // Q B-fragments straight from global: qa[qgroup][khalf]
  short8 qa[2][2];
  #pragma unroll
  for (int qg = 0; qg < 2; ++qg)
    #pragma unroll
    for (int hf = 0; hf < 2; ++hf)
      qa[qg][hf] = *(const short8*)(Qg + (size_t)(q0 + wave * 32 + qg * 16 + l15) * HD + hf * 32 + quad * 8);

  const int srow = tid >> 2, cb0 = (tid & 3) * 16;
  // stage tile 0 into buffer 0
  {
    uint4 ka = *(const uint4*)(Kg + (size_t)srow * HD + cb0);
    uint4 kc = *(const uint4*)(Kg + (size_t)srow * HD + cb0 + 8);
    uint4 va = *(const uint4*)(Vg + (size_t)srow * T + cb0);
    uint4 vc = *(const uint4*)(Vg + (size_t)srow * T + cb0 + 8);
    *(uint4*)&Ks[0][swz(srow, cb0)]     = ka;
    *(uint4*)&Ks[0][swz(srow, cb0 + 8)] = kc;
    *(uint4*)&Vt[0][swz(srow, cb0)]     = va;
    *(uint4*)&Vt[0][swz(srow, cb0 + 8)] = vc;
  }
  __syncthreads();

  f32x4 o[2][4];
  #pragma unroll
  for (int qg = 0; qg < 2; ++qg)
    #pragma unroll
    for (int nt = 0; nt < 4; ++nt) o[qg][nt] = (f32x4){0.f, 0.f, 0.f, 0.f};
  float lsum[2] = {0.f, 0.f};

  for (int kt = 0; kt < T; kt += 64) {
    const int cur = (kt >> 6) & 1;
    const bool more = (kt + 64) < T;
    uint4 nk0, nk1, nv0, nv1;
    if (more) {
      nk0 = *(const uint4*)(Kg + (size_t)(kt + 64 + srow) * HD + cb0);
      nk1 = *(const uint4*)(Kg + (size_t)(kt + 64 + srow) * HD + cb0 + 8);
      nv0 = *(const uint4*)(Vg + (size_t)srow * T + kt + 64 + cb0);
      nv1 = *(const uint4*)(Vg + (size_t)srow * T + kt + 64 + cb0 + 8);
    }

    // S^T: C col = q (l15), row = kc (quad*4+r)
    f32x4 ss[2][4];
    #pragma unroll
    for (int qg = 0; qg < 2; ++qg)
      #pragma unroll
      for (int mt = 0; mt < 4; ++mt) ss[qg][mt] = (f32x4){0.f, 0.f, 0.f, 0.f};
    #pragma unroll
    for (int mt = 0; mt < 4; ++mt) {
      int row = mt * 16 + l15;
      short8 ka0 = *(const short8*)&Ks[cur][swz(row, quad * 8)];
      short8 ka1 = *(const short8*)&Ks[cur][swz(row, 32 + quad * 8)];
      ss[0][mt] = __builtin_amdgcn_mfma_f32_16x16x32_bf16(ka0, qa[0][0], ss[0][mt], 0, 0, 0);
      ss[0][mt] = __builtin_amdgcn_mfma_f32_16x16x32_bf16(ka1, qa[0][1], ss[0][mt], 0, 0, 0);
      ss[1][mt] = __builtin_amdgcn_mfma_f32_16x16x32_bf16(ka0, qa[1][0], ss[1][mt], 0, 0, 0);
      ss[1][mt] = __builtin_amdgcn_mfma_f32_16x16x32_bf16(ka1, qa[1][1], ss[1][mt], 0, 0, 0);
    }

    // exp + denominator partial + packed bf16 P write (no cross-lane ops)
    #pragma unroll
    for (int qg = 0; qg < 2; ++qg) {
      int rp = wave * 32 + qg * 16 + l15;
      #pragma unroll
      for (int mt = 0; mt < 4; ++mt) {
        float p0 = __expf(ss[qg][mt][0]);
        float p1 = __expf(ss[qg][mt][1]);
        float p2 = __expf(ss[qg][mt][2]);
        float p3 = __expf(ss[qg][mt][3]);
        lsum[qg] += (p0 + p1) + (p2 + p3);
        uint2 w2;
        w2.x = pack_bf2(p0, p1);
        w2.y = pack_bf2(p2, p3);
        *(uint2*)&Ps[swz(rp, mt * 16 + quad * 4)] = w2;
      }
    }

    // PV: A = P (wave-private rows), B = V^T
    short8 pa[2][2];
    #pragma unroll
    for (int qg = 0; qg < 2; ++qg) {
      int rp = wave * 32 + qg * 16 + l15;
      pa[qg][0] = *(const short8*)&Ps[swz(rp, quad * 8)];
      pa[qg][1] = *(const short8*)&Ps[swz(rp, 32 + quad * 8)];
    }
    #pragma unroll
    for (int nt = 0; nt < 4; ++nt) {
      int vr = nt * 16 + l15;
      short8 vb0 = *(const short8*)&Vt[cur][swz(vr, quad * 8)];
      short8 vb1 = *(const short8*)&Vt[cur][swz(vr, 32 + quad * 8)];
      o[0][nt] = __builtin_amdgcn_mfma_f32_16x16x32_bf16(pa[0][0], vb0, o[0][nt], 0, 0, 0);
      o[0][nt] = __builtin_amdgcn_mfma_f32_16x16x32_bf16(pa[0][1], vb1, o[0][nt], 0, 0, 0);
      o[1][nt] = __builtin_amdgcn_mfma_f32_16x16x32_bf16(pa[1][0], vb0, o[1][nt], 0, 0, 0);
      o[1][nt] = __builtin_amdgcn_mfma_f32_16x16x32_bf16(pa[1][1], vb1, o[1][nt], 0, 0, 0);
    }

    if (more) {
      const int nxt = cur ^ 1;
      *(uint4*)&Ks[nxt][swz(srow, cb0)]     = nk0;
      *(uint4*)&Ks[nxt][swz(srow, cb0 + 8)] = nk1;
      *(uint4*)&Vt[nxt][swz(srow, cb0)]     = nv0;
      *(uint4*)&Vt[nxt][swz(srow, cb0 + 8)] = nv1;
    }
    __syncthreads();
  }

  // denominator: lane's partial covers its quad's kc rows; reduce across quads
  #pragma unroll
  for (int qg = 0; qg < 2; ++qg) {
    lsum[qg] += __shfl_xor(lsum[qg], 16);
    lsum[qg] += __shfl_xor(lsum[qg], 32);
  }

  const int b = bh / H, h = bh % H;
  #pragma unroll
  for (int qg = 0; qg < 2; ++qg) {
    #pragma unroll
    for (int r = 0; r < 4; ++r) {
      float lr = __shfl(lsum[qg], quad * 4 + r);
      float inv = 1.0f / lr;
      int t = q0 + wave * 32 + qg * 16 + quad * 4 + r;
      size_t base = ((size_t)b * T + t) * E + h * HD;
      cbuf[base + l15]      = f2bf(o[qg][0][r] * inv);
      cbuf[base + 16 + l15] = f2bf(o[qg][1][r] * inv);
      cbuf[base + 32 + l15] = f2bf(o[qg][2][r] * inv);
      cbuf[base + 48 + l15] = f2bf(o[qg][3][r] * inv);
    }
  }
}

// ---------------------------------------------------------------------------
// Output projection, 128x128 bf16 MFMA tile, fp32 out with bias.
// ---------------------------------------------------------------------------
__global__ __launch_bounds__(256) void out_gemm(
    const ushort_t* __restrict__ Xc, const ushort_t* __restrict__ Wob,
    const float* __restrict__ bo, float* __restrict__ out)
{
  __shared__ __align__(16) ushort_t Xs[128 * 32];
  __shared__ __align__(16) ushort_t Ws[128 * 32];
  const int tid  = threadIdx.x;
  const int wave = tid >> 6;
  const int lane = tid & 63;
  const int l15  = lane & 15, quad = lane >> 4;
  const int ww = wave >> 1, wn = wave & 1;
  const int n0 = blockIdx.x * 128;
  const int m0 = blockIdx.y * 128;

  f32x4 acc[4][4];
  #pragma unroll
  for (int i = 0; i < 4; ++i)
    #pragma unroll
    for (int j = 0; j < 4; ++j) acc[i][j] = (f32x4){0.f, 0.f, 0.f, 0.f};

  const int srow = tid >> 1, scc = (tid & 1) * 16;

  for (int k0 = 0; k0 < E; k0 += 32) {
    uint4 xa = *(const uint4*)(Xc + (size_t)(m0 + srow) * E + k0 + scc);
    uint4 xc = *(const uint4*)(Xc + (size_t)(m0 + srow) * E + k0 + scc + 8);
    uint4 wa = *(const uint4*)(Wob + (size_t)(n0 + srow) * E + k0 + scc);
    uint4 wc = *(const uint4*)(Wob + (size_t)(n0 + srow) * E + k0 + scc + 8);
    *(uint4*)&Xs[swz32(srow, scc)]     = xa;
    *(uint4*)&Xs[swz32(srow, scc + 8)] = xc;
    *(uint4*)&Ws[swz32(srow, scc)]     = wa;
    *(uint4*)&Ws[swz32(srow, scc + 8)] = wc;
    __syncthreads();
    short8 a[4];
    #pragma unroll
    for (int mt = 0; mt < 4; ++mt)
      a[mt] = *(const short8*)&Xs[swz32(ww * 64 + mt * 16 + l15, quad * 8)];
    #pragma unroll
    for (int nt = 0; nt < 4; ++nt) {
      short8 bb = *(const short8*)&Ws[swz32(wn * 64 + nt * 16 + l15, quad * 8)];
      #pragma unroll
      for (int mt = 0; mt < 4; ++mt)
        acc[mt][nt] = __builtin_amdgcn_mfma_f32_16x16x32_bf16(a[mt], bb, acc[mt][nt], 0, 0, 0);
    }
    __syncthreads();
  }

  float bias[4];
  #pragma unroll
  for (int nt = 0; nt < 4; ++nt) bias[nt] = bo[n0 + wn * 64 + nt * 16 + l15];
  #pragma unroll
  for (int mt = 0; mt < 4; ++mt) {
    #pragma unroll
    for (int r = 0; r < 4; ++r) {
      int m = m0 + ww * 64 + mt * 16 + quad * 4 + r;
      float* op = out + (size_t)m * E + n0 + wn * 64;
      op[l15]      = acc[mt][0][r] + bias[0];
      op[16 + l15] = acc[mt][1][r] + bias[1];
      op[32 + l15] = acc[mt][2][r] + bias[2];
      op[48 + l15] = acc[mt][3][r] + bias[3];
    }
  }
}

// ---------------------------------------------------------------------------
extern "C" void kernel_launch(void* const* d_in, const int* in_sizes, int n_in,
                              void* d_out, int out_size, void* d_ws, size_t ws_size,
                              hipStream_t stream) {
  (void)in_sizes; (void)n_in; (void)out_size; (void)ws_size;
  const float* X    = (const float*)d_in[0];
  const float* rope = (const float*)d_in[1];
  const float* Wq   = (const float*)d_in[2];
  const float* Wk   = (const float*)d_in[3];
  const float* Wv   = (const float*)d_in[4];
  const float* Wo   = (const float*)d_in[5];
  const float* bo   = (const float*)d_in[6];
  float* out = (float*)d_out;

  const size_t NX = (size_t)B * T * E;
  const size_t NW = (size_t)E * E;
  ushort_t* Xb  = (ushort_t*)d_ws;
  ushort_t* Wqb = Xb  + NX;
  ushort_t* Wkb = Wqb + NW;
  ushort_t* Wvb = Wkb + NW;
  ushort_t* Wob = Wvb + NW;
  ushort_t* qb  = Wob + NW;
  ushort_t* kb  = qb  + NX;
  ushort_t* vtb = kb  + NX;
  ushort_t* cb  = vtb + NX;

  const int total4 = (int)((NX + 4 * NW) / 4);
  cvt_all<<<total4 / 256, 256, 0, stream>>>(X, Wq, Wk, Wv, Wo, Xb, Wqb, Wkb, Wvb, Wob);

  qkv_gemm<<<dim3(E / 128, (B * T) / 128, 3), 256, 0, stream>>>(
      Xb, Wqb, Wkb, Wvb, rope, qb, kb, vtb);
  attn_kernel<<<dim3(T / 128, B * H), 256, 0, stream>>>(qb, kb, vtb, cb);
  out_gemm<<<dim3(E / 128, (B * T) / 128), 256, 0, stream>>>(cb, Wob, bo, out);
}

// Round 5
// 183.181 us; speedup vs baseline: 1.0880x; 1.0880x over previous
//
#include <hip/hip_runtime.h>
#include <hip/hip_bf16.h>

typedef unsigned short ushort_t;
typedef __attribute__((ext_vector_type(8))) short short8;
typedef __attribute__((ext_vector_type(4))) float f32x4;

constexpr int B  = 2;
constexpr int T  = 2048;
constexpr int E  = 768;
constexpr int H  = 12;
constexpr int HD = 64;

__device__ __forceinline__ ushort_t f2bf(float x) {
  unsigned int u = __float_as_uint(x);
  u += 0x7fffu + ((u >> 16) & 1u);
  return (ushort_t)(u >> 16);
}

__device__ __forceinline__ unsigned int pack_bf2(float a, float b) {
  __hip_bfloat162 h = __float22bfloat162_rn(float2{a, b});
  return *(unsigned int*)&h;
}

// XOR-swizzled LDS index, 64-ushort rows (attention): 16B chunks, chunk ^= row&7.
__device__ __forceinline__ int swz(int row, int col) {
  return row * 64 + ((((col >> 3) ^ (row & 7)) << 3) | (col & 7));
}
// XOR-swizzled LDS index, 32-ushort rows (GEMM k-step 32): chunk ^= row&3.
__device__ __forceinline__ int swz32(int row, int col) {
  return row * 32 + ((((col >> 3) ^ (row & 3)) << 3) | (col & 7));
}

// ---------------------------------------------------------------------------
// Fused: fp32->bf16 convert for X + 4 weights, AND fp32 cos/sin rope tables.
// ---------------------------------------------------------------------------
__global__ __launch_bounds__(256) void cvt_all(
    const float* __restrict__ X,  const float* __restrict__ Wq,
    const float* __restrict__ Wk, const float* __restrict__ Wv,
    const float* __restrict__ Wo, const float* __restrict__ rope,
    ushort_t* __restrict__ Xb,  ushort_t* __restrict__ Wqb,
    ushort_t* __restrict__ Wkb, ushort_t* __restrict__ Wvb,
    ushort_t* __restrict__ Wob, float* __restrict__ ct, float* __restrict__ st)
{
  constexpr int NX4 = (B * T * E) / 4;
  constexpr int NW4 = (E * E) / 4;
  constexpr int NC4 = NX4 + 4 * NW4;
  int i = blockIdx.x * 256 + threadIdx.x;
  if (i < NC4) {
    const float* s; ushort_t* d; int j;
    if (i < NX4) { s = X; d = Xb; j = i; }
    else {
      int t = i - NX4;
      int w = t / NW4; j = t - w * NW4;
      s = (w == 0) ? Wq : (w == 1) ? Wk : (w == 2) ? Wv : Wo;
      d = (w == 0) ? Wqb : (w == 1) ? Wkb : (w == 2) ? Wvb : Wob;
    }
    float4 v = ((const float4*)s)[j];
    ushort4 o;
    o.x = f2bf(v.x); o.y = f2bf(v.y); o.z = f2bf(v.z); o.w = f2bf(v.w);
    ((ushort4*)d)[j] = o;
  } else {
    int j = (i - NC4) * 4;   // rope index, T*ROT total
    float4 f = *(const float4*)(rope + j);
    float c, s;
    sincosf(f.x, &s, &c); ct[j+0] = c; st[j+0] = s;
    sincosf(f.y, &s, &c); ct[j+1] = c; st[j+1] = s;
    sincosf(f.z, &s, &c); ct[j+2] = c; st[j+2] = s;
    sincosf(f.w, &s, &c); ct[j+3] = c; st[j+3] = s;
  }
}

// ---------------------------------------------------------------------------
// QKV projection, bf16 MFMA. Tile 128(M)x64(N=one head), K-step 32, 4 waves
// each 32Mx64N. Rotary via precomputed tables. Epilogue goes through an LDS
// transpose so ALL global stores are coalesced uint4:
//   q/k -> (bh,t,d) row-major;  v -> (bh,d,t) transposed.
// ---------------------------------------------------------------------------
__global__ __launch_bounds__(256) void qkv_gemm(
    const ushort_t* __restrict__ Xb,
    const ushort_t* __restrict__ Wqb, const ushort_t* __restrict__ Wkb,
    const ushort_t* __restrict__ Wvb,
    const float* __restrict__ ct, const float* __restrict__ st,
    ushort_t* __restrict__ qb, ushort_t* __restrict__ kb, ushort_t* __restrict__ vtb)
{
  // union: staging Xs(128x32)+Ws(64x32)=6144 | Tr q/k 128x64=8192 | Trv 64x132=8448
  __shared__ __align__(16) ushort_t smem[64 * 132];
  ushort_t* Xs = smem;
  ushort_t* Ws = smem + 128 * 32;
  const int tid  = threadIdx.x;
  const int wave = tid >> 6;
  const int lane = tid & 63;
  const int l15  = lane & 15, quad = lane >> 4;
  const int n0 = blockIdx.x * 64;
  const int m0 = blockIdx.y * 128;
  const int z  = blockIdx.z;
  const ushort_t* Wt = (z == 0) ? Wqb : (z == 1) ? Wkb : Wvb;
  const int h = n0 >> 6;

  f32x4 acc[2][4];
  #pragma unroll
  for (int i = 0; i < 2; ++i)
    #pragma unroll
    for (int j = 0; j < 4; ++j) acc[i][j] = (f32x4){0.f, 0.f, 0.f, 0.f};

  const int srX = tid >> 1, scX = (tid & 1) * 16;
  const int srW = tid >> 2, scW = (tid & 3) * 8;

  for (int k0 = 0; k0 < E; k0 += 32) {
    uint4 xa = *(const uint4*)(Xb + (size_t)(m0 + srX) * E + k0 + scX);
    uint4 xc = *(const uint4*)(Xb + (size_t)(m0 + srX) * E + k0 + scX + 8);
    uint4 wa = *(const uint4*)(Wt + (size_t)(n0 + srW) * E + k0 + scW);
    *(uint4*)&Xs[swz32(srX, scX)]     = xa;
    *(uint4*)&Xs[swz32(srX, scX + 8)] = xc;
    *(uint4*)&Ws[swz32(srW, scW)]     = wa;
    __syncthreads();
    short8 a[2];
    #pragma unroll
    for (int mt = 0; mt < 2; ++mt)
      a[mt] = *(const short8*)&Xs[swz32(wave * 32 + mt * 16 + l15, quad * 8)];
    #pragma unroll
    for (int nt = 0; nt < 4; ++nt) {
      short8 bb = *(const short8*)&Ws[swz32(nt * 16 + l15, quad * 8)];
      #pragma unroll
      for (int mt = 0; mt < 2; ++mt)
        acc[mt][nt] = __builtin_amdgcn_mfma_f32_16x16x32_bf16(a[mt], bb, acc[mt][nt], 0, 0, 0);
    }
    __syncthreads();
  }

  const float qscale = (z == 0) ? 0.125f : 1.0f;
  if (z < 2) {
    // rotate in regs, write LDS (t,d) layout, then coalesced store
    #pragma unroll
    for (int mt = 0; mt < 2; ++mt) {
      #pragma unroll
      for (int r = 0; r < 4; ++r) {
        int mloc = wave * 32 + mt * 16 + quad * 4 + r;
        int t = (m0 + mloc) & (T - 1);
        float s0 = acc[mt][0][r] * qscale;
        float s1 = acc[mt][1][r] * qscale;
        float c0v = ct[t * 32 + l15],      sn0 = st[t * 32 + l15];
        float c1v = ct[t * 32 + 16 + l15], sn1 = st[t * 32 + 16 + l15];
        smem[mloc * 64 + l15]      = f2bf(s0 * c0v - s1 * sn0);
        smem[mloc * 64 + 16 + l15] = f2bf(s1 * c1v + s0 * sn1);
        smem[mloc * 64 + 32 + l15] = f2bf(acc[mt][2][r] * qscale);
        smem[mloc * 64 + 48 + l15] = f2bf(acc[mt][3][r] * qscale);
      }
    }
    __syncthreads();
    ushort_t* dst = (z == 0) ? qb : kb;
    int row = tid >> 1, half = (tid & 1) * 32;
    int m = m0 + row, b = m >> 11, t = m & (T - 1);
    size_t base = ((size_t)(b * H + h) * T + t) * HD + half;
    #pragma unroll
    for (int c = 0; c < 32; c += 8)
      *(uint4*)(dst + base + c) = *(const uint4*)&smem[row * 64 + half + c];
  } else {
    // V: rotate, write LDS transposed (d,t) stride 132, coalesced store
    #pragma unroll
    for (int mt = 0; mt < 2; ++mt) {
      #pragma unroll
      for (int r = 0; r < 4; ++r) {
        int mloc = wave * 32 + mt * 16 + quad * 4 + r;
        int t = (m0 + mloc) & (T - 1);
        float s0 = acc[mt][0][r], s1 = acc[mt][1][r];
        float c0v = ct[t * 32 + l15],      sn0 = st[t * 32 + l15];
        float c1v = ct[t * 32 + 16 + l15], sn1 = st[t * 32 + 16 + l15];
        smem[(l15)      * 132 + mloc] = f2bf(s0 * c0v - s1 * sn0);
        smem[(16 + l15) * 132 + mloc] = f2bf(s1 * c1v + s0 * sn1);
        smem[(32 + l15) * 132 + mloc] = f2bf(acc[mt][2][r]);
        smem[(48 + l15) * 132 + mloc] = f2bf(acc[mt][3][r]);
      }
    }
    __syncthreads();
    int b = m0 >> 11, t0 = m0 & (T - 1);
    int d = tid >> 2, c0 = (tid & 3) * 32;
    size_t obase = ((size_t)(b * H + h) * HD + d) * (size_t)T + t0 + c0;
    #pragma unroll
    for (int c = 0; c < 32; c += 8)
      *(uint4*)(vtb + obase + c) = *(const uint4*)&smem[d * 132 + c0 + c];
  }
}

// ---------------------------------------------------------------------------
// Flash attention. Block = 64 q-rows x bh (768 blocks = 3/CU); 4 waves, wave
// owns 16 q. Double-buffered K/V (ONE barrier/tile), XOR-swizzled LDS,
// Q fragments from global, static max, per-lane denominator.
// ---------------------------------------------------------------------------
__global__ __launch_bounds__(256, 4) void attn_kernel(
    const ushort_t* __restrict__ qbuf, const ushort_t* __restrict__ kbuf,
    const ushort_t* __restrict__ vtbuf, ushort_t* __restrict__ cbuf)
{
  __shared__ __align__(16) ushort_t Ks[2][64 * 64];
  __shared__ __align__(16) ushort_t Vt[2][64 * 64];
  __shared__ __align__(16) ushort_t Ps[64 * 64];
  const int tid  = threadIdx.x;
  const int wave = tid >> 6;
  const int lane = tid & 63;
  const int l15  = lane & 15, quad = lane >> 4;
  const int q0 = blockIdx.x * 64;
  const int bh = blockIdx.y;
  const ushort_t* Qg = qbuf  + (size_t)bh * T * HD;
  const ushort_t* Kg = kbuf  + (size_t)bh * T * HD;
  const ushort_t* Vg = vtbuf + (size_t)bh * HD * T;

  short8 qa[2];
  #pragma unroll
  for (int hf = 0; hf < 2; ++hf)
    qa[hf] = *(const short8*)(Qg + (size_t)(q0 + wave * 16 + l15) * HD + hf * 32 + quad * 8);

  const int srow = tid >> 2, cb0 = (tid & 3) * 16;
  {
    uint4 ka = *(const uint4*)(Kg + (size_t)srow * HD + cb0);
    uint4 kc = *(const uint4*)(Kg + (size_t)srow * HD + cb0 + 8);
    uint4 va = *(const uint4*)(Vg + (size_t)srow * T + cb0);
    uint4 vc = *(const uint4*)(Vg + (size_t)srow * T + cb0 + 8);
    *(uint4*)&Ks[0][swz(srow, cb0)]     = ka;
    *(uint4*)&Ks[0][swz(srow, cb0 + 8)] = kc;
    *(uint4*)&Vt[0][swz(srow, cb0)]     = va;
    *(uint4*)&Vt[0][swz(srow, cb0 + 8)] = vc;
  }
  __syncthreads();

  f32x4 o[4];
  #pragma unroll
  for (int nt = 0; nt < 4; ++nt) o[nt] = (f32x4){0.f, 0.f, 0.f, 0.f};
  float lsum = 0.f;

  for (int kt = 0; kt < T; kt += 64) {
    const int cur = (kt >> 6) & 1;
    const bool more = (kt + 64) < T;
    uint4 nk0, nk1, nv0, nv1;
    if (more) {
      nk0 = *(const uint4*)(Kg + (size_t)(kt + 64 + srow) * HD + cb0);
      nk1 = *(const uint4*)(Kg + (size_t)(kt + 64 + srow) * HD + cb0 + 8);
      nv0 = *(const uint4*)(Vg + (size_t)srow * T + kt + 64 + cb0);
      nv1 = *(const uint4*)(Vg + (size_t)srow * T + kt + 64 + cb0 + 8);
    }

    // S^T: C row = kc (quad*4+r within mt tile), col = q (l15)
    f32x4 ss[4];
    #pragma unroll
    for (int mt = 0; mt < 4; ++mt) ss[mt] = (f32x4){0.f, 0.f, 0.f, 0.f};
    #pragma unroll
    for (int mt = 0; mt < 4; ++mt) {
      int row = mt * 16 + l15;
      short8 ka0 = *(const short8*)&Ks[cur][swz(row, quad * 8)];
      short8 ka1 = *(const short8*)&Ks[cur][swz(row, 32 + quad * 8)];
      ss[mt] = __builtin_amdgcn_mfma_f32_16x16x32_bf16(ka0, qa[0], ss[mt], 0, 0, 0);
      ss[mt] = __builtin_amdgcn_mfma_f32_16x16x32_bf16(ka1, qa[1], ss[mt], 0, 0, 0);
    }

    // exp + per-lane denominator + packed bf16 P write (no cross-lane ops)
    const int rp = wave * 16 + l15;
    #pragma unroll
    for (int mt = 0; mt < 4; ++mt) {
      float p0 = __expf(ss[mt][0]);
      float p1 = __expf(ss[mt][1]);
      float p2 = __expf(ss[mt][2]);
      float p3 = __expf(ss[mt][3]);
      lsum += (p0 + p1) + (p2 + p3);
      uint2 w2;
      w2.x = pack_bf2(p0, p1);
      w2.y = pack_bf2(p2, p3);
      *(uint2*)&Ps[swz(rp, mt * 16 + quad * 4)] = w2;
    }

    // PV: A = P (wave-private rows), B = V^T
    short8 pa0 = *(const short8*)&Ps[swz(rp, quad * 8)];
    short8 pa1 = *(const short8*)&Ps[swz(rp, 32 + quad * 8)];
    #pragma unroll
    for (int nt = 0; nt < 4; ++nt) {
      int vr = nt * 16 + l15;
      short8 vb0 = *(const short8*)&Vt[cur][swz(vr, quad * 8)];
      short8 vb1 = *(const short8*)&Vt[cur][swz(vr, 32 + quad * 8)];
      o[nt] = __builtin_amdgcn_mfma_f32_16x16x32_bf16(pa0, vb0, o[nt], 0, 0, 0);
      o[nt] = __builtin_amdgcn_mfma_f32_16x16x32_bf16(pa1, vb1, o[nt], 0, 0, 0);
    }

    if (more) {
      const int nxt = cur ^ 1;
      *(uint4*)&Ks[nxt][swz(srow, cb0)]     = nk0;
      *(uint4*)&Ks[nxt][swz(srow, cb0 + 8)] = nk1;
      *(uint4*)&Vt[nxt][swz(srow, cb0)]     = nv0;
      *(uint4*)&Vt[nxt][swz(srow, cb0 + 8)] = nv1;
    }
    __syncthreads();
  }

  lsum += __shfl_xor(lsum, 16);
  lsum += __shfl_xor(lsum, 32);

  const int b = bh / H, h = bh % H;
  #pragma unroll
  for (int r = 0; r < 4; ++r) {
    float lr = __shfl(lsum, quad * 4 + r);
    float inv = 1.0f / lr;
    int t = q0 + wave * 16 + quad * 4 + r;
    size_t base = ((size_t)b * T + t) * E + h * HD;
    cbuf[base + l15]      = f2bf(o[0][r] * inv);
    cbuf[base + 16 + l15] = f2bf(o[1][r] * inv);
    cbuf[base + 32 + l15] = f2bf(o[2][r] * inv);
    cbuf[base + 48 + l15] = f2bf(o[3][r] * inv);
  }
}

// ---------------------------------------------------------------------------
// Output projection, 128x64 bf16 MFMA tile (384 blocks), fp32 out with bias.
// ---------------------------------------------------------------------------
__global__ __launch_bounds__(256) void out_gemm(
    const ushort_t* __restrict__ Xc, const ushort_t* __restrict__ Wob,
    const float* __restrict__ bo, float* __restrict__ out)
{
  __shared__ __align__(16) ushort_t Xs[128][40];
  __shared__ __align__(16) ushort_t Ws[64][40];
  const int tid  = threadIdx.x;
  const int wave = tid >> 6;
  const int lane = tid & 63;
  const int l15  = lane & 15, quad = lane >> 4;
  const int n0 = blockIdx.x * 64;
  const int m0 = blockIdx.y * 128;

  f32x4 acc[2][4];
  #pragma unroll
  for (int i = 0; i < 2; ++i)
    #pragma unroll
    for (int j = 0; j < 4; ++j) acc[i][j] = (f32x4){0.f, 0.f, 0.f, 0.f};

  const int srX = tid >> 1, scX = (tid & 1) * 16;
  const int srW = tid >> 2, scW = (tid & 3) * 8;

  for (int k0 = 0; k0 < E; k0 += 32) {
    *(uint4*)&Xs[srX][scX]     = *(const uint4*)(Xc + (size_t)(m0 + srX) * E + k0 + scX);
    *(uint4*)&Xs[srX][scX + 8] = *(const uint4*)(Xc + (size_t)(m0 + srX) * E + k0 + scX + 8);
    *(uint4*)&Ws[srW][scW]     = *(const uint4*)(Wob + (size_t)(n0 + srW) * E + k0 + scW);
    __syncthreads();
    #pragma unroll
    for (int mt = 0; mt < 2; ++mt) {
      short8 a = *(const short8*)&Xs[wave * 32 + mt * 16 + l15][quad * 8];
      #pragma unroll
      for (int nt = 0; nt < 4; ++nt) {
        short8 bb = *(const short8*)&Ws[nt * 16 + l15][quad * 8];
        acc[mt][nt] = __builtin_amdgcn_mfma_f32_16x16x32_bf16(a, bb, acc[mt][nt], 0, 0, 0);
      }
    }
    __syncthreads();
  }

  float bias[4];
  #pragma unroll
  for (int nt = 0; nt < 4; ++nt) bias[nt] = bo[n0 + nt * 16 + l15];
  #pragma unroll
  for (int mt = 0; mt < 2; ++mt) {
    #pragma unroll
    for (int r = 0; r < 4; ++r) {
      int m = m0 + wave * 32 + mt * 16 + quad * 4 + r;
      float* op = out + (size_t)m * E + n0;
      op[l15]      = acc[mt][0][r] + bias[0];
      op[16 + l15] = acc[mt][1][r] + bias[1];
      op[32 + l15] = acc[mt][2][r] + bias[2];
      op[48 + l15] = acc[mt][3][r] + bias[3];
    }
  }
}

// ---------------------------------------------------------------------------
extern "C" void kernel_launch(void* const* d_in, const int* in_sizes, int n_in,
                              void* d_out, int out_size, void* d_ws, size_t ws_size,
                              hipStream_t stream) {
  (void)in_sizes; (void)n_in; (void)out_size; (void)ws_size;
  const float* X    = (const float*)d_in[0];
  const float* rope = (const float*)d_in[1];
  const float* Wq   = (const float*)d_in[2];
  const float* Wk   = (const float*)d_in[3];
  const float* Wv   = (const float*)d_in[4];
  const float* Wo   = (const float*)d_in[5];
  const float* bo   = (const float*)d_in[6];
  float* out = (float*)d_out;

  const size_t NX = (size_t)B * T * E;
  const size_t NW = (size_t)E * E;
  const size_t NR = (size_t)T * 32;
  ushort_t* Xb  = (ushort_t*)d_ws;
  ushort_t* Wqb = Xb  + NX;
  ushort_t* Wkb = Wqb + NW;
  ushort_t* Wvb = Wkb + NW;
  ushort_t* Wob = Wvb + NW;
  ushort_t* qb  = Wob + NW;
  ushort_t* kb  = qb  + NX;
  ushort_t* vtb = kb  + NX;
  ushort_t* cb  = vtb + NX;
  float* ct = (float*)(cb + NX);
  float* st = ct + NR;

  const int total4 = (int)((NX + 4 * NW + NR) / 4);   // 1392640 -> 5440 blocks
  cvt_all<<<total4 / 256, 256, 0, stream>>>(X, Wq, Wk, Wv, Wo, rope,
                                            Xb, Wqb, Wkb, Wvb, Wob, ct, st);

  qkv_gemm<<<dim3(E / 64, (B * T) / 128, 3), 256, 0, stream>>>(
      Xb, Wqb, Wkb, Wvb, ct, st, qb, kb, vtb);
  attn_kernel<<<dim3(T / 64, B * H), 256, 0, stream>>>(qb, kb, vtb, cb);
  out_gemm<<<dim3(E / 64, (B * T) / 128), 256, 0, stream>>>(cb, Wob, bo, out);
}